// Round 14
// baseline (41.670 us; speedup 1.0000x reference)
//
#include <hip/hip_runtime.h>

// DepthLossForImgBEV: weighted BCE over (B,N,D,H,W) depth logits vs one-hot
// bucketized GT depth, reduced to a scalar mean * 3.0.
//
// B=2 N=6 D=112 H=64 W=176.  depth: (B,N*D,H,W) f32 (60.6 MB, ~half
// L3-resident); depth_gt: (B,N,H,W) f32 (cache-hot).
//
// R11 measured: k1 ~= 12 us, k2 + dispatch gap ~= 7 us of R10's 20.56.
// Fused variants R3/R9/R12/R13 ALL compiled to VGPR 16/32/40/44: the fused
// tail tips the compiler into serializing the 16-deep load batch (~650 GB/s
// latency-bound; even L3-hot replays 45 us). R10's per-i keep-alive asm never
// actually forced batching -- per-i volatile fences may legally interleave as
// load[i];fence[i];load[i+1];... with only ~2 float4s live.
//
// R14: hand-written asm loads. 16x global_load_dwordx4 as ordered asm
// volatile with 16 distinct f32x4 outputs, then ONE s_waitcnt vmcnt(0), then
// sched_barrier(0) (rule #18: hipcc hoists register-only uses past inline-asm
// waitcnt -- sched_barrier is the required fence). All 64 dest VGPRs are live
// across the wait by dataflow -> the allocator CANNOT serialize; 16 loads in
// flight by construction. Tail = R13's O(N) block-0 poller (proven correct).

namespace {

typedef float f32x4 __attribute__((ext_vector_type(4)));

constexpr int B_ = 2, N_ = 6, D_ = 112, H_ = 64, W_ = 176;
constexpr int HW_   = H_ * W_;          // 11264
constexpr int NHWQ_ = HW_ / 4;          // 2816 float4 quads per image plane
constexpr int DPC_  = 16, NCH_ = 7;     // 7 d-chunks x 16 slices = 112
constexpr int NBN_  = B_ * N_;          // 12
constexpr long long TOT_ = (long long)NBN_ * D_ * HW_;   // 15,138,816
constexpr int NTHR_ = NBN_ * NCH_ * NHWQ_;               // 236,544
constexpr int NBLK_ = NTHR_ / 256;                       // 924 blocks
constexpr float SCALE_ = (float)(3.0 / (double)TOT_);    // 3.0 / numel
constexpr int MAGIC_ = 0x5A17ED0F;      // != 0, != 0xAAAAAAAA

// bce = min(softplus(+-x), 100) * w;  softplus(x) = relu(x) + log1p(exp(-|x|))
__device__ __forceinline__ float term(float x, float w, bool hit) {
    float c = __logf(1.0f + __expf(-fabsf(x)));          // shared log term
    float r = hit ? fmaxf(-x, 0.0f) : fmaxf(x, 0.0f);
    return w * fminf(c + r, 100.0f);
}

__device__ __forceinline__ int bucket(float g) {
    int i = (int)floorf((g - 2.0f) * 2.0f);   // (g - DBOUND0) / DBOUND2
    return i < 0 ? 0 : (i > D_ ? D_ : i);     // clip [0,D]; D never matches d
}

__global__ __launch_bounds__(256) void depth_loss_fused(
        const float* __restrict__ gt, const float* __restrict__ dp,
        float* __restrict__ part, int* __restrict__ flags,
        float* __restrict__ out) {
    const int t    = blockIdx.x * 256 + threadIdx.x;
    const int hwq  = t % NHWQ_;           // quad within image plane
    const int rest = t / NHWQ_;
    const int ch   = rest % NCH_;         // which 16-slice d-chunk
    const int bn   = rest / NCH_;         // (b*N + n)
    const int hw   = hwq * 4;
    const int d0   = ch * DPC_;

    const float4 g = *reinterpret_cast<const float4*>(gt + bn * HW_ + hw);
    const float* p = dp + ((bn * D_ + d0) * HW_ + hw);

    // 16 hand-issued loads: ordered volatile asm, 16 distinct f32x4 dests.
    f32x4 xv[DPC_];
    #pragma unroll
    for (int i = 0; i < DPC_; ++i) {
        const float* pi = p + (size_t)i * HW_;
        asm volatile("global_load_dwordx4 %0, %1, off"
                     : "=v"(xv[i]) : "v"(pi));
    }
    asm volatile("s_waitcnt vmcnt(0)" ::: "memory");
    __builtin_amdgcn_sched_barrier(0);   // rule #18: block use-hoisting past the wait

    const float w0 = (g.x != 0.0f) ? 1.0f : 0.0f;
    const float w1 = (g.y != 0.0f) ? 1.0f : 0.0f;
    const float w2 = (g.z != 0.0f) ? 1.0f : 0.0f;
    const float w3 = (g.w != 0.0f) ? 1.0f : 0.0f;
    const int  i0 = bucket(g.x), i1 = bucket(g.y), i2 = bucket(g.z), i3 = bucket(g.w);

    float s = 0.0f;
    #pragma unroll
    for (int i = 0; i < DPC_; ++i) {
        const int d = d0 + i;
        s += term(xv[i][0], w0, d == i0);
        s += term(xv[i][1], w1, d == i1);
        s += term(xv[i][2], w2, d == i2);
        s += term(xv[i][3], w3, d == i3);
    }

    // block reduce -> one partial per block
    #pragma unroll
    for (int off = 32; off > 0; off >>= 1) s += __shfl_down(s, off, 64);
    __shared__ float ls[4];
    if ((threadIdx.x & 63) == 0) ls[threadIdx.x >> 6] = s;
    __syncthreads();

    if (blockIdx.x != 0) {
        // publish partial, then flag; exit immediately (no scan traffic)
        if (threadIdx.x == 0) {
            __hip_atomic_store(&part[blockIdx.x], (ls[0] + ls[1]) + (ls[2] + ls[3]),
                               __ATOMIC_RELAXED, __HIP_MEMORY_SCOPE_AGENT);
            __hip_atomic_store(&flags[blockIdx.x], MAGIC_,
                               __ATOMIC_RELEASE, __HIP_MEMORY_SCOPE_AGENT);
        }
        return;
    }

    // ---- block 0: the only poller/finisher ----
    if (threadIdx.x == 0)
        part[0] = (ls[0] + ls[1]) + (ls[2] + ls[3]);

    for (;;) {   // poll own subset (<=4 flags/thread) until all peers published
        bool mine = true;
        for (int i = threadIdx.x; i < NBLK_; i += 256)
            if (i != 0)
                mine &= (__hip_atomic_load(&flags[i], __ATOMIC_RELAXED,
                                           __HIP_MEMORY_SCOPE_AGENT) == MAGIC_);
        if (__syncthreads_and(mine)) break;
        __builtin_amdgcn_s_sleep(8);     // backoff: keep coherent traffic low
    }
    __threadfence();   // acquire: order flag reads before partial reads

    float r = 0.0f;
    for (int i = threadIdx.x; i < NBLK_; i += 256)   // fixed-order -> deterministic
        r += (i == 0) ? part[0]
                      : __hip_atomic_load(&part[i], __ATOMIC_RELAXED,
                                          __HIP_MEMORY_SCOPE_AGENT);
    #pragma unroll
    for (int off = 32; off > 0; off >>= 1) r += __shfl_down(r, off, 64);
    if ((threadIdx.x & 63) == 0) ls[threadIdx.x >> 6] = r;
    __syncthreads();
    if (threadIdx.x == 0)
        out[0] = ((ls[0] + ls[1]) + (ls[2] + ls[3])) * SCALE_;

    // clear flags for the next replay (visible at kernel end)
    for (int i = threadIdx.x; i < NBLK_; i += 256)
        __hip_atomic_store(&flags[i], 0, __ATOMIC_RELAXED,
                           __HIP_MEMORY_SCOPE_AGENT);
}

}  // namespace

extern "C" void kernel_launch(void* const* d_in, const int* in_sizes, int n_in,
                              void* d_out, int out_size, void* d_ws, size_t ws_size,
                              hipStream_t stream) {
    const float* gt = (const float*)d_in[0];   // depth_gt (B,N,H,W)
    const float* dp = (const float*)d_in[1];   // depth (B,N*D,H,W)
    float* part = (float*)d_ws;                // 924 floats @ ws+0
    int* flags  = (int*)((char*)d_ws + 4096);  // 924 ints  @ ws+4096
    float* out  = (float*)d_out;
    depth_loss_fused<<<NBLK_, 256, 0, stream>>>(gt, dp, part, flags, out);
}